// Round 7
// baseline (237.688 us; speedup 1.0000x reference)
//
#include <hip/hip_runtime.h>
#include <hip/hip_bf16.h>
#include <math.h>

#define N_NODES 50000
#define N_EDGES 1600000
#define IN_FEAT 256
#define HIDDEN 128
#define N_CLASSES 16

#define ECHUNK 2048
#define NCHK 782    // ceil(1600000/2048)
#define NBKT 196    // ceil(50000/256) buckets of 256 nodes
#define BCAP 10240  // per-bucket capacity: mean 8192, std ~90 -> +23 sigma
#define CSTR 16     // cursor stride (ints): 1 counter per 64B line

typedef __attribute__((ext_vector_type(8))) short short8;   // 8 bf16 (A/B frag)
typedef __attribute__((ext_vector_type(4))) float floatx4;  // C/D frag

// bf16 round-to-nearest-even (scalar integer path)
__device__ __forceinline__ unsigned short f2bf(float f) {
    unsigned u = __float_as_uint(f);
    return (unsigned short)((u + 0x7fffu + ((u >> 16) & 1u)) >> 16);
}

// HW packed fp32->bf16x2
__device__ __forceinline__ unsigned pk2bf(float a, float b) {
    __hip_bfloat162 h = __float22bfloat162_rn(make_float2(a, b));
    union { __hip_bfloat162 h; unsigned u; } cv;
    cv.h = h;
    return cv.u;
}

__device__ __forceinline__ float bflo(unsigned u) { return __uint_as_float(u << 16); }
__device__ __forceinline__ float bfhi(unsigned u) { return __uint_as_float(u & 0xffff0000u); }

// ---------------------------------------------------------------------------
// Prep: fixed-capacity buckets. 782 blocks (2048 edges each) for >1 block/CU;
// cursor counters padded to 1/line. Blocks 0..127 transpose W1 -> w1t.
// ---------------------------------------------------------------------------
__global__ __launch_bounds__(256) void scatter_edges2(const int* __restrict__ src,
                                                      const int* __restrict__ dst,
                                                      int* __restrict__ cursor,   // [256*CSTR], zeroed
                                                      unsigned int* __restrict__ sorted,
                                                      const float* __restrict__ W1,
                                                      unsigned short* __restrict__ w1t) {
    __shared__ int hloc[256];
    int t = threadIdx.x;
    hloc[t] = 0;
    if (blockIdx.x < HIDDEN)
        w1t[blockIdx.x * IN_FEAT + t] = f2bf(W1[t * HIDDEN + blockIdx.x]);
    __syncthreads();
    int base = blockIdx.x * ECHUNK;
    int end = min(base + ECHUNK, N_EDGES);
    for (int i = base + t; i < end; i += 256)
        atomicAdd(&hloc[dst[i] >> 8], 1);
    __syncthreads();
    int cnt = hloc[t];
    int lbase = 0;
    if (cnt > 0) lbase = t * BCAP + atomicAdd(&cursor[t * CSTR], cnt);  // block's base in bucket t
    __syncthreads();
    hloc[t] = lbase;  // reuse as local cursor
    __syncthreads();
    for (int i = base + t; i < end; i += 256) {
        int d = dst[i];
        int s = src[i];
        int pos = atomicAdd(&hloc[d >> 8], 1);
        sorted[pos] = ((unsigned)d << 16) | (unsigned)s;
    }
}

// 512 threads/block -> 16 edges/thread serial passes.
__global__ __launch_bounds__(512) void build_csr2(const unsigned int* __restrict__ sorted,
                                                  const int* __restrict__ cursor,
                                                  int* __restrict__ rs,
                                                  int* __restrict__ re,
                                                  float* __restrict__ dis,
                                                  unsigned short* __restrict__ csr_src) {
    __shared__ int cnt[256];
    __shared__ int roff[256];
    int t = threadIdx.x;      // 0..511
    int bkt = blockIdx.x;
    int ebase = bkt * BCAP;
    int eend = ebase + cursor[bkt * CSTR];
    if (t < 256) cnt[t] = 0;
    __syncthreads();
    for (int i = ebase + t; i < eend; i += 512)
        atomicAdd(&cnt[(sorted[i] >> 16) & 255], 1);
    __syncthreads();
    int v = 0;
    if (t < 256) { v = cnt[t]; roff[t] = v; }
    __syncthreads();
    for (int off = 1; off < 256; off <<= 1) {
        int x = (t < 256 && t >= off) ? roff[t - off] : 0;
        __syncthreads();
        if (t < 256) roff[t] += x;
        __syncthreads();
    }
    if (t < 256) {
        int excl = roff[t] - v;
        int node = bkt * 256 + t;
        if (node < N_NODES) {
            rs[node] = ebase + excl;
            re[node] = ebase + excl + v;
            dis[node] = 1.0f / sqrtf((float)(v + 1));  // +1 self loop
        }
        cnt[t] = ebase + excl;  // reuse as cursor
    }
    __syncthreads();
    for (int i = ebase + t; i < eend; i += 512) {
        unsigned e = sorted[i];
        int pos = atomicAdd(&cnt[(e >> 16) & 255], 1);
        csr_src[pos] = (unsigned short)(e & 0xffffu);
    }
}

// ---------------------------------------------------------------------------
// GEMM1 v7: 32-row x 128-col block, whole 32x256 x-panel staged up front
// (8 global_load_lds per wave, 33.3KB LDS), ONE barrier, then 8 barrier-free
// K-steps from LDS. Kills the per-kk vmcnt(0)+barrier drain of v6 (the
// double-buffer was defeated by __syncthreads draining the just-issued
// stage). Wave w owns cols w*32..w*32+31 == slice plane w. 4 blocks/CU.
// ---------------------------------------------------------------------------
#define XCHDW 260   // dwords per 8-row chunk: 8*32 + 4 pad
#define KBLK (4 * XCHDW)   // dwords per kk block (4 chunks = 32 rows)

__global__ __launch_bounds__(256) void gemm1_mfma(const float* __restrict__ x,
                                                  const unsigned short* __restrict__ w1t,
                                                  const float* __restrict__ dis,
                                                  unsigned int* __restrict__ g1) {
    __shared__ float xs[8 * KBLK];   // 33,280 B
    int tid = threadIdx.x;
    int w = tid >> 6;
    int lane = tid & 63;
    int quad = lane >> 4;
    int c = lane & 15;
    int row_base = blockIdx.x * 32;
    int col_base = w * 32;           // wave w -> cols w*32.., slice w

    // staging: wave w stages rows row_base+8w .. +8w+7, all K (8 issues)
    int st_row = min(row_base + 8 * w + (lane >> 3), N_NODES - 1);
    const float* gp1 = x + (size_t)st_row * IN_FEAT + (lane & 7) * 4;
#pragma unroll
    for (int kk = 0; kk < 8; ++kk)
        __builtin_amdgcn_global_load_lds(
            (const __attribute__((address_space(1))) void*)(gp1 + kk * 32),
            (__attribute__((address_space(3))) void*)&xs[kk * KBLK + w * XCHDW], 16, 0, 0);

    floatx4 acc[2][2] = {};
    const unsigned short* bp[2];
#pragma unroll
    for (int nt = 0; nt < 2; ++nt)
        bp[nt] = w1t + (size_t)(col_base + nt * 16 + c) * IN_FEAT + quad * 8;

    int dwoff[2];
#pragma unroll
    for (int rt = 0; rt < 2; ++rt) {
        int rit = rt * 16 + c;
        dwoff[rt] = (rit >> 3) * XCHDW + (rit & 7) * 32 + quad * 8;
    }

    __syncthreads();   // single drain: all 32 stage issues

#pragma unroll
    for (int kk = 0; kk < 8; ++kk) {
        short8 b[2];
#pragma unroll
        for (int nt = 0; nt < 2; ++nt)
            b[nt] = *(const short8*)(bp[nt] + kk * 32);
        short8 a[2];
#pragma unroll
        for (int rt = 0; rt < 2; ++rt) {
            float4 f0 = *(const float4*)&xs[kk * KBLK + dwoff[rt]];
            float4 f1 = *(const float4*)&xs[kk * KBLK + dwoff[rt] + 4];
            union { short8 s; unsigned u[4]; } au;
            au.u[0] = pk2bf(f0.x, f0.y);
            au.u[1] = pk2bf(f0.z, f0.w);
            au.u[2] = pk2bf(f1.x, f1.y);
            au.u[3] = pk2bf(f1.z, f1.w);
            a[rt] = au.s;
        }
#pragma unroll
        for (int rt = 0; rt < 2; ++rt)
#pragma unroll
            for (int nt = 0; nt < 2; ++nt)
                acc[rt][nt] = __builtin_amdgcn_mfma_f32_16x16x32_bf16(a[rt], b[nt], acc[rt][nt], 0, 0, 0);
    }

    // Epilogue: dis scale, pair adjacent cols via shfl, pack bf16x2, store
    // slice-major. C/D layout: col = lane&15, row = quad*4 + reg.
    bool evenlane = (lane & 1) == 0;
#pragma unroll
    for (int rt = 0; rt < 2; ++rt) {
#pragma unroll
        for (int reg = 0; reg < 4; ++reg) {
            int row = row_base + rt * 16 + quad * 4 + reg;
            float dv = dis[min(row, N_NODES - 1)];
#pragma unroll
            for (int nt = 0; nt < 2; ++nt) {
                float v = acc[rt][nt][reg] * dv;
                float vo = __shfl_xor(v, 1);
                if (evenlane && row < N_NODES) {
                    unsigned pkd = (unsigned)f2bf(v) | ((unsigned)f2bf(vo) << 16);
                    int col = col_base + nt * 16 + c;  // even
                    g1[(size_t)(col >> 5) * (N_NODES * 16) + (size_t)row * 16 + ((col & 31) >> 1)] = pkd;
                }
            }
        }
    }
}

// ---------------------------------------------------------------------------
// Aggregation 1 + bias + ReLU + GEMM2 partial. Feature-sliced, XCD-pinned.
// Gather loop FROZEN (measured random-gather wall ~8 TB/s of 64B visits).
// v7: epilogue writes dis-scaled partials straight into the single g2
// buffer via native fp32 global atomics -> g2_reduce dispatch eliminated.
// g2 is zero-initialized by the launch-front memset.
// ---------------------------------------------------------------------------
__global__ __launch_bounds__(256) void agg1_sliced(const uint4* __restrict__ g1,
                                                   const int* __restrict__ rs,
                                                   const int* __restrict__ re,
                                                   const unsigned short* __restrict__ csr_src,
                                                   const float* __restrict__ dis,
                                                   const float* __restrict__ b1,
                                                   const float* __restrict__ W2,
                                                   float* __restrict__ g2) {
    __shared__ float w2s[32 * 16];      // this slice's W2 rows (2 KB)
    __shared__ float rbuf[4][16][36];   // per wave/group r vector (32 feats + pad)
    int tid = threadIdx.x;
    int bi = blockIdx.x;
    int bucket = bi >> 4;               // 196
    int xcd = bi & 7;
    int slice = xcd >> 1;               // XCD pair {2s,2s+1} -> slice s
    int quarter = ((bi >> 3) & 1) * 2 + (xcd & 1);

    for (int i = tid; i < 512; i += 256) w2s[i] = W2[slice * 512 + i];
    __syncthreads();

    int wave = tid >> 6, lane = tid & 63;
    int g = lane >> 2, m4 = lane & 3;   // group g owns a node; lane m4 covers feats 8*m4..8*m4+7
    const uint4* plane = g1 + (size_t)slice * (N_NODES * 4);
    int node = bucket * 256 + quarter * 64 + wave * 16 + g;
    bool alive = (node < N_NODES);
    float dvs = 0.f;

#define ACC8(u) do { a0 += bflo((u).x); a1 += bfhi((u).x); a2 += bflo((u).y); a3 += bfhi((u).y); \
                     a4 += bflo((u).z); a5 += bfhi((u).z); a6 += bflo((u).w); a7 += bfhi((u).w); } while (0)
#define GATH(IV, U0, U1, U2, U3) do {                       \
        int j0_ = (int)((IV).x & 0xffffu);                  \
        int j1_ = (int)((IV).x >> 16);                      \
        int j2_ = (int)((IV).y & 0xffffu);                  \
        int j3_ = (int)((IV).y >> 16);                      \
        U0 = plane[(size_t)j0_ * 4 + m4];                   \
        U1 = plane[(size_t)j1_ * 4 + m4];                   \
        U2 = plane[(size_t)j2_ * 4 + m4];                   \
        U3 = plane[(size_t)j3_ * 4 + m4];                   \
    } while (0)

    if (alive) {
        uint4 su = plane[(size_t)node * 4 + m4];   // self loop (g1 carries dis[src])
        float a0 = bflo(su.x), a1 = bfhi(su.x), a2 = bflo(su.y), a3 = bfhi(su.y);
        float a4 = bflo(su.z), a5 = bfhi(su.z), a6 = bflo(su.w), a7 = bfhi(su.w);
        int e = rs[node], e1v = re[node];
        // peel to 4-edge alignment so uint2 index loads are 8B-aligned
        while ((e & 3) && e < e1v) {
            int j = csr_src[e];
            uint4 u = plane[(size_t)j * 4 + m4];
            ACC8(u);
            ++e;
        }
        int nb = (e1v - e) >> 2;   // full batches of 4
        if (nb >= 2) {
            uint2 Ia = *(const uint2*)&csr_src[e];
            uint2 Ib = *(const uint2*)&csr_src[e + 4];
            uint4 A0, A1, A2, A3, B0, B1, B2, B3;
            GATH(Ia, A0, A1, A2, A3);
            GATH(Ib, B0, B1, B2, B3);
            __builtin_amdgcn_sched_barrier(0);
            int b = 2;
            while (b + 2 <= nb) {
                Ia = *(const uint2*)&csr_src[e + 4 * b];      // idx for next A, early
                ACC8(A0); ACC8(A1); ACC8(A2); ACC8(A3);       // consume A (hides Ia)
                GATH(Ia, A0, A1, A2, A3);                     // reissue A
                __builtin_amdgcn_sched_barrier(0);
                Ib = *(const uint2*)&csr_src[e + 4 * b + 4];  // idx for next B, early
                ACC8(B0); ACC8(B1); ACC8(B2); ACC8(B3);       // consume B (hides Ib)
                GATH(Ib, B0, B1, B2, B3);                     // reissue B
                __builtin_amdgcn_sched_barrier(0);
                b += 2;
            }
            int rem = nb - b;   // 0 or 1
            ACC8(A0); ACC8(A1); ACC8(A2); ACC8(A3);
            if (rem) {
                Ia = *(const uint2*)&csr_src[e + 4 * b];
                GATH(Ia, A0, A1, A2, A3);
            }
            ACC8(B0); ACC8(B1); ACC8(B2); ACC8(B3);
            if (rem) { ACC8(A0); ACC8(A1); ACC8(A2); ACC8(A3); }
            e += 4 * nb;
        } else if (nb >= 1) {
            uint2 Iv = *(const uint2*)&csr_src[e];
            uint4 U0, U1, U2, U3;
            GATH(Iv, U0, U1, U2, U3);
            ACC8(U0); ACC8(U1); ACC8(U2); ACC8(U3);
            e += 4;
        }
        while (e < e1v) {   // tail 0..3 edges
            int j = csr_src[e];
            uint4 u = plane[(size_t)j * 4 + m4];
            ACC8(u);
            ++e;
        }

        // bias + ReLU, publish r (lane owns feats 8*m4..8*m4+7)
        float dv = dis[node];
        dvs = dv;
        float4 bb0 = *(const float4*)&b1[slice * 32 + 8 * m4];
        float4 bb1 = *(const float4*)&b1[slice * 32 + 8 * m4 + 4];
        float4 r0, r1;
        r0.x = fmaxf(fmaf(dv, a0, bb0.x), 0.f);
        r0.y = fmaxf(fmaf(dv, a1, bb0.y), 0.f);
        r0.z = fmaxf(fmaf(dv, a2, bb0.z), 0.f);
        r0.w = fmaxf(fmaf(dv, a3, bb0.w), 0.f);
        r1.x = fmaxf(fmaf(dv, a4, bb1.x), 0.f);
        r1.y = fmaxf(fmaf(dv, a5, bb1.y), 0.f);
        r1.z = fmaxf(fmaf(dv, a6, bb1.z), 0.f);
        r1.w = fmaxf(fmaf(dv, a7, bb1.w), 0.f);
        *(float4*)&rbuf[wave][g][8 * m4] = r0;
        *(float4*)&rbuf[wave][g][8 * m4 + 4] = r1;
    }
    __builtin_amdgcn_sched_barrier(0);   // wave-synchronous LDS: keep reads after writes
    if (alive) {
        // GEMM2 partial: lane m4 computes classes 4*m4..4*m4+3 over all 32 feats
        float p0 = 0.f, p1 = 0.f, p2 = 0.f, p3 = 0.f;
#pragma unroll
        for (int fb = 0; fb < 8; ++fb) {
            float4 rv = *(const float4*)&rbuf[wave][g][fb * 4];
            float4 w0 = *(const float4*)&w2s[(fb * 4 + 0) * 16 + 4 * m4];
            float4 w1 = *(const float4*)&w2s[(fb * 4 + 1) * 16 + 4 * m4];
            float4 w2 = *(const float4*)&w2s[(fb * 4 + 2) * 16 + 4 * m4];
            float4 w3 = *(const float4*)&w2s[(fb * 4 + 3) * 16 + 4 * m4];
            p0 = fmaf(rv.x, w0.x, p0); p1 = fmaf(rv.x, w0.y, p1);
            p2 = fmaf(rv.x, w0.z, p2); p3 = fmaf(rv.x, w0.w, p3);
            p0 = fmaf(rv.y, w1.x, p0); p1 = fmaf(rv.y, w1.y, p1);
            p2 = fmaf(rv.y, w1.z, p2); p3 = fmaf(rv.y, w1.w, p3);
            p0 = fmaf(rv.z, w2.x, p0); p1 = fmaf(rv.z, w2.y, p1);
            p2 = fmaf(rv.z, w2.z, p2); p3 = fmaf(rv.z, w2.w, p3);
            p0 = fmaf(rv.w, w3.x, p0); p1 = fmaf(rv.w, w3.y, p1);
            p2 = fmaf(rv.w, w3.z, p2); p3 = fmaf(rv.w, w3.w, p3);
        }
        // dis-scaled accumulate into the single g2 (native fp32 atomics)
        float* go = g2 + (size_t)node * 16 + 4 * m4;
        unsafeAtomicAdd(go + 0, dvs * p0);
        unsafeAtomicAdd(go + 1, dvs * p1);
        unsafeAtomicAdd(go + 2, dvs * p2);
        unsafeAtomicAdd(go + 3, dvs * p3);
    }
#undef GATH
#undef ACC8
}

// ---------------------------------------------------------------------------
// Aggregation 2 + bias + logits + softmax. Depth-2 ping-pong with direct
// uint2 index loads. g2 (3.2 MB, final values) L2/LLC-resident.
// ---------------------------------------------------------------------------
__global__ __launch_bounds__(256) void agg2_softmax(const float4* __restrict__ g2,
                                                    const int* __restrict__ rs,
                                                    const int* __restrict__ re,
                                                    const unsigned short* __restrict__ csr_src,
                                                    const float* __restrict__ dis,
                                                    const float* __restrict__ b2,
                                                    float* __restrict__ out) {
    int tid = threadIdx.x;
    int wave = tid >> 6, lane = tid & 63;
    int g = lane >> 2, m4 = lane & 3;   // group owns a node; lane m4 covers classes 4*m4..4*m4+3
    int node = blockIdx.x * 64 + wave * 16 + g;
    if (node >= N_NODES) return;

    float4 acc = g2[(size_t)node * 4 + m4];   // self loop

#define ACC4(u) do { acc.x += (u).x; acc.y += (u).y; acc.z += (u).z; acc.w += (u).w; } while (0)
#define GATH4(IV, U0, U1, U2, U3) do {                      \
        int j0_ = (int)((IV).x & 0xffffu);                  \
        int j1_ = (int)((IV).x >> 16);                      \
        int j2_ = (int)((IV).y & 0xffffu);                  \
        int j3_ = (int)((IV).y >> 16);                      \
        U0 = g2[(size_t)j0_ * 4 + m4];                      \
        U1 = g2[(size_t)j1_ * 4 + m4];                      \
        U2 = g2[(size_t)j2_ * 4 + m4];                      \
        U3 = g2[(size_t)j3_ * 4 + m4];                      \
    } while (0)

    int e = rs[node], e1v = re[node];
    while ((e & 3) && e < e1v) {
        int j = csr_src[e];
        float4 u = g2[(size_t)j * 4 + m4];
        ACC4(u);
        ++e;
    }
    int nb = (e1v - e) >> 2;
    if (nb >= 2) {
        uint2 Ia = *(const uint2*)&csr_src[e];
        uint2 Ib = *(const uint2*)&csr_src[e + 4];
        float4 A0, A1, A2, A3, B0, B1, B2, B3;
        GATH4(Ia, A0, A1, A2, A3);
        GATH4(Ib, B0, B1, B2, B3);
        __builtin_amdgcn_sched_barrier(0);
        int b = 2;
        while (b + 2 <= nb) {
            Ia = *(const uint2*)&csr_src[e + 4 * b];
            ACC4(A0); ACC4(A1); ACC4(A2); ACC4(A3);
            GATH4(Ia, A0, A1, A2, A3);
            __builtin_amdgcn_sched_barrier(0);
            Ib = *(const uint2*)&csr_src[e + 4 * b + 4];
            ACC4(B0); ACC4(B1); ACC4(B2); ACC4(B3);
            GATH4(Ib, B0, B1, B2, B3);
            __builtin_amdgcn_sched_barrier(0);
            b += 2;
        }
        int rem = nb - b;
        ACC4(A0); ACC4(A1); ACC4(A2); ACC4(A3);
        if (rem) {
            Ia = *(const uint2*)&csr_src[e + 4 * b];
            GATH4(Ia, A0, A1, A2, A3);
        }
        ACC4(B0); ACC4(B1); ACC4(B2); ACC4(B3);
        if (rem) { ACC4(A0); ACC4(A1); ACC4(A2); ACC4(A3); }
        e += 4 * nb;
    } else if (nb >= 1) {
        uint2 Iv = *(const uint2*)&csr_src[e];
        float4 U0, U1, U2, U3;
        GATH4(Iv, U0, U1, U2, U3);
        ACC4(U0); ACC4(U1); ACC4(U2); ACC4(U3);
        e += 4;
    }
    while (e < e1v) {
        int j = csr_src[e];
        float4 u = g2[(size_t)j * 4 + m4];
        ACC4(u);
        ++e;
    }
#undef GATH4
#undef ACC4

    float dv = dis[node];
    float4 bb = *(const float4*)&b2[4 * m4];
    float4 lg;
    lg.x = fmaf(dv, acc.x, bb.x);
    lg.y = fmaf(dv, acc.y, bb.y);
    lg.z = fmaf(dv, acc.z, bb.z);
    lg.w = fmaf(dv, acc.w, bb.w);
    ((float4*)out)[(size_t)node * 4 + m4] = lg;

    // softmax over 16 classes = 4 lanes x 4
    float m = fmaxf(fmaxf(lg.x, lg.y), fmaxf(lg.z, lg.w));
    m = fmaxf(m, __shfl_xor(m, 1));
    m = fmaxf(m, __shfl_xor(m, 2));
    float4 ex;
    ex.x = expf(lg.x - m); ex.y = expf(lg.y - m);
    ex.z = expf(lg.z - m); ex.w = expf(lg.w - m);
    float s = (ex.x + ex.y) + (ex.z + ex.w);
    s += __shfl_xor(s, 1);
    s += __shfl_xor(s, 2);
    float inv = 1.0f / s;
    ex.x *= inv; ex.y *= inv; ex.z *= inv; ex.w *= inv;
    ((float4*)out)[(size_t)N_NODES * 4 + (size_t)node * 4 + m4] = ex;
}

// ---------------------------------------------------------------------------

extern "C" void kernel_launch(void* const* d_in, const int* in_sizes, int n_in,
                              void* d_out, int out_size, void* d_ws, size_t ws_size,
                              hipStream_t stream) {
    const float* x  = (const float*)d_in[0];
    const int*   ei = (const int*)d_in[1];
    const float* W1 = (const float*)d_in[2];
    const float* b1 = (const float*)d_in[3];
    const float* W2 = (const float*)d_in[4];
    const float* b2 = (const float*)d_in[5];
    float* out = (float*)d_out;

    char* ws = (char*)d_ws;
    size_t off = 0;
    auto alloc = [&](size_t bytes) -> char* {
        char* p = ws + off;
        off = (off + bytes + 511) & ~(size_t)511;
        return p;
    };
    // cursor + g2 adjacent: one memset zeroes both (16KB + 3.2MB)
    int*   cursor   = (int*)alloc(256 * CSTR * 4);
    float* g2       = (float*)alloc((size_t)N_NODES * N_CLASSES * 4);
    float* dis      = (float*)alloc(N_NODES * 4);
    int*   rs       = (int*)alloc(N_NODES * 4);
    int*   re       = (int*)alloc(N_NODES * 4);
    unsigned short* w1t = (unsigned short*)alloc((size_t)HIDDEN * IN_FEAT * 2);
    unsigned short* csr_src = (unsigned short*)alloc((size_t)NBKT * BCAP * 2);  // holey
    unsigned int* g1 = (unsigned int*)alloc((size_t)N_NODES * 64 * 4);          // slice-major: 4 x [N][16dw]
    // sorted edges (196*10240*4 = 8.0MB) alias g1's slab (12.8MB): dead before gemm1.
    unsigned int* sorted = (unsigned int*)g1;
    (void)ws_size; (void)in_sizes; (void)n_in; (void)out_size;

    const int* src = ei;
    const int* dst = ei + N_EDGES;

    size_t zspan = (size_t)((char*)(g2 + (size_t)N_NODES * N_CLASSES) - (char*)cursor);
    hipMemsetAsync(cursor, 0, zspan, stream);
    scatter_edges2<<<NCHK, 256, 0, stream>>>(src, dst, cursor, sorted, W1, w1t);
    build_csr2<<<NBKT, 512, 0, stream>>>(sorted, cursor, rs, re, dis, csr_src);

    gemm1_mfma<<<(N_NODES + 31) / 32, 256, 0, stream>>>(x, w1t, dis, g1);
    agg1_sliced<<<NBKT * 16, 256, 0, stream>>>((const uint4*)g1, rs, re, csr_src, dis, b1, W2, g2);
    agg2_softmax<<<N_NODES / 64 + 1, 256, 0, stream>>>((const float4*)g2, rs, re, csr_src, dis, b2, out);
}

// Round 8
// 230.163 us; speedup vs baseline: 1.0327x; 1.0327x over previous
//
#include <hip/hip_runtime.h>
#include <hip/hip_bf16.h>
#include <math.h>

#define N_NODES 50000
#define N_EDGES 1600000
#define IN_FEAT 256
#define HIDDEN 128
#define N_CLASSES 16

#define ECHUNK 2048
#define NCHK 782    // ceil(1600000/2048)
#define NBKT 196    // ceil(50000/256) buckets of 256 nodes
#define BCAP 10240  // per-bucket capacity: mean 8192, std ~90 -> +23 sigma
#define CSTR 16     // cursor stride (ints): 1 counter per 64B line

typedef __attribute__((ext_vector_type(8))) short short8;   // 8 bf16 (A/B frag)
typedef __attribute__((ext_vector_type(4))) float floatx4;  // C/D frag

// bf16 round-to-nearest-even (scalar integer path)
__device__ __forceinline__ unsigned short f2bf(float f) {
    unsigned u = __float_as_uint(f);
    return (unsigned short)((u + 0x7fffu + ((u >> 16) & 1u)) >> 16);
}

// HW packed fp32->bf16x2
__device__ __forceinline__ unsigned pk2bf(float a, float b) {
    __hip_bfloat162 h = __float22bfloat162_rn(make_float2(a, b));
    union { __hip_bfloat162 h; unsigned u; } cv;
    cv.h = h;
    return cv.u;
}

__device__ __forceinline__ float bflo(unsigned u) { return __uint_as_float(u << 16); }
__device__ __forceinline__ float bfhi(unsigned u) { return __uint_as_float(u & 0xffff0000u); }

// ---------------------------------------------------------------------------
// Prep: fixed-capacity buckets. 782 blocks (2048 edges each); cursor
// counters padded to 1/line. Blocks 0..127 transpose W1 -> w1t.
// ---------------------------------------------------------------------------
__global__ __launch_bounds__(256) void scatter_edges2(const int* __restrict__ src,
                                                      const int* __restrict__ dst,
                                                      int* __restrict__ cursor,   // [256*CSTR], zeroed
                                                      unsigned int* __restrict__ sorted,
                                                      const float* __restrict__ W1,
                                                      unsigned short* __restrict__ w1t) {
    __shared__ int hloc[256];
    int t = threadIdx.x;
    hloc[t] = 0;
    if (blockIdx.x < HIDDEN)
        w1t[blockIdx.x * IN_FEAT + t] = f2bf(W1[t * HIDDEN + blockIdx.x]);
    __syncthreads();
    int base = blockIdx.x * ECHUNK;
    int end = min(base + ECHUNK, N_EDGES);
    for (int i = base + t; i < end; i += 256)
        atomicAdd(&hloc[dst[i] >> 8], 1);
    __syncthreads();
    int cnt = hloc[t];
    int lbase = 0;
    if (cnt > 0) lbase = t * BCAP + atomicAdd(&cursor[t * CSTR], cnt);  // block's base in bucket t
    __syncthreads();
    hloc[t] = lbase;  // reuse as local cursor
    __syncthreads();
    for (int i = base + t; i < end; i += 256) {
        int d = dst[i];
        int s = src[i];
        int pos = atomicAdd(&hloc[d >> 8], 1);
        sorted[pos] = ((unsigned)d << 16) | (unsigned)s;
    }
}

// 512 threads/block -> 16 edges/thread serial passes.
__global__ __launch_bounds__(512) void build_csr2(const unsigned int* __restrict__ sorted,
                                                  const int* __restrict__ cursor,
                                                  int* __restrict__ rs,
                                                  int* __restrict__ re,
                                                  float* __restrict__ dis,
                                                  unsigned short* __restrict__ csr_src) {
    __shared__ int cnt[256];
    __shared__ int roff[256];
    int t = threadIdx.x;      // 0..511
    int bkt = blockIdx.x;
    int ebase = bkt * BCAP;
    int eend = ebase + cursor[bkt * CSTR];
    if (t < 256) cnt[t] = 0;
    __syncthreads();
    for (int i = ebase + t; i < eend; i += 512)
        atomicAdd(&cnt[(sorted[i] >> 16) & 255], 1);
    __syncthreads();
    int v = 0;
    if (t < 256) { v = cnt[t]; roff[t] = v; }
    __syncthreads();
    for (int off = 1; off < 256; off <<= 1) {
        int x = (t < 256 && t >= off) ? roff[t - off] : 0;
        __syncthreads();
        if (t < 256) roff[t] += x;
        __syncthreads();
    }
    if (t < 256) {
        int excl = roff[t] - v;
        int node = bkt * 256 + t;
        if (node < N_NODES) {
            rs[node] = ebase + excl;
            re[node] = ebase + excl + v;
            dis[node] = 1.0f / sqrtf((float)(v + 1));  // +1 self loop
        }
        cnt[t] = ebase + excl;  // reuse as cursor
    }
    __syncthreads();
    for (int i = ebase + t; i < eend; i += 512) {
        unsigned e = sorted[i];
        int pos = atomicAdd(&cnt[(e >> 16) & 255], 1);
        csr_src[pos] = (unsigned short)(e & 0xffffu);
    }
}

// ---------------------------------------------------------------------------
// GEMM1 v7 (kept): 32-row x 128-col block, whole 32x256 x-panel staged up
// front (8 global_load_lds per wave, 33.3KB LDS), ONE barrier, then 8
// barrier-free K-steps. Wave w owns cols w*32..w*32+31 == slice plane w.
// ---------------------------------------------------------------------------
#define XCHDW 260   // dwords per 8-row chunk: 8*32 + 4 pad
#define KBLK (4 * XCHDW)   // dwords per kk block (4 chunks = 32 rows)

__global__ __launch_bounds__(256) void gemm1_mfma(const float* __restrict__ x,
                                                  const unsigned short* __restrict__ w1t,
                                                  const float* __restrict__ dis,
                                                  unsigned int* __restrict__ g1) {
    __shared__ float xs[8 * KBLK];   // 33,280 B
    int tid = threadIdx.x;
    int w = tid >> 6;
    int lane = tid & 63;
    int quad = lane >> 4;
    int c = lane & 15;
    int row_base = blockIdx.x * 32;
    int col_base = w * 32;           // wave w -> cols w*32.., slice w

    // staging: wave w stages rows row_base+8w .. +8w+7, all K (8 issues)
    int st_row = min(row_base + 8 * w + (lane >> 3), N_NODES - 1);
    const float* gp1 = x + (size_t)st_row * IN_FEAT + (lane & 7) * 4;
#pragma unroll
    for (int kk = 0; kk < 8; ++kk)
        __builtin_amdgcn_global_load_lds(
            (const __attribute__((address_space(1))) void*)(gp1 + kk * 32),
            (__attribute__((address_space(3))) void*)&xs[kk * KBLK + w * XCHDW], 16, 0, 0);

    floatx4 acc[2][2] = {};
    const unsigned short* bp[2];
#pragma unroll
    for (int nt = 0; nt < 2; ++nt)
        bp[nt] = w1t + (size_t)(col_base + nt * 16 + c) * IN_FEAT + quad * 8;

    int dwoff[2];
#pragma unroll
    for (int rt = 0; rt < 2; ++rt) {
        int rit = rt * 16 + c;
        dwoff[rt] = (rit >> 3) * XCHDW + (rit & 7) * 32 + quad * 8;
    }

    __syncthreads();   // single drain: all 32 stage issues

#pragma unroll
    for (int kk = 0; kk < 8; ++kk) {
        short8 b[2];
#pragma unroll
        for (int nt = 0; nt < 2; ++nt)
            b[nt] = *(const short8*)(bp[nt] + kk * 32);
        short8 a[2];
#pragma unroll
        for (int rt = 0; rt < 2; ++rt) {
            float4 f0 = *(const float4*)&xs[kk * KBLK + dwoff[rt]];
            float4 f1 = *(const float4*)&xs[kk * KBLK + dwoff[rt] + 4];
            union { short8 s; unsigned u[4]; } au;
            au.u[0] = pk2bf(f0.x, f0.y);
            au.u[1] = pk2bf(f0.z, f0.w);
            au.u[2] = pk2bf(f1.x, f1.y);
            au.u[3] = pk2bf(f1.z, f1.w);
            a[rt] = au.s;
        }
#pragma unroll
        for (int rt = 0; rt < 2; ++rt)
#pragma unroll
            for (int nt = 0; nt < 2; ++nt)
                acc[rt][nt] = __builtin_amdgcn_mfma_f32_16x16x32_bf16(a[rt], b[nt], acc[rt][nt], 0, 0, 0);
    }

    // Epilogue: dis scale, pair adjacent cols via shfl, pack bf16x2, store
    // slice-major. C/D layout: col = lane&15, row = quad*4 + reg.
    bool evenlane = (lane & 1) == 0;
#pragma unroll
    for (int rt = 0; rt < 2; ++rt) {
#pragma unroll
        for (int reg = 0; reg < 4; ++reg) {
            int row = row_base + rt * 16 + quad * 4 + reg;
            float dv = dis[min(row, N_NODES - 1)];
#pragma unroll
            for (int nt = 0; nt < 2; ++nt) {
                float v = acc[rt][nt][reg] * dv;
                float vo = __shfl_xor(v, 1);
                if (evenlane && row < N_NODES) {
                    unsigned pkd = (unsigned)f2bf(v) | ((unsigned)f2bf(vo) << 16);
                    int col = col_base + nt * 16 + c;  // even
                    g1[(size_t)(col >> 5) * (N_NODES * 16) + (size_t)row * 16 + ((col & 31) >> 1)] = pkd;
                }
            }
        }
    }
}

// ---------------------------------------------------------------------------
// Aggregation 1 + bias + ReLU + per-slice GEMM2 partial. Feature-sliced,
// XCD-pinned. Gather loop FROZEN (random-gather wall). v8: epilogue back to
// g2p plane stores (R7's global atomics cost +18us: WRITE 12.5->50MB).
// Launched as TWO half-grid dispatches (bi0 = 0, NBKT*8) so agg1 instances
// drop to ~26us -> any hidden >28us kernel must surface in the top-5.
// ---------------------------------------------------------------------------
__global__ __launch_bounds__(256) void agg1_sliced(const uint4* __restrict__ g1,
                                                   const int* __restrict__ rs,
                                                   const int* __restrict__ re,
                                                   const unsigned short* __restrict__ csr_src,
                                                   const float* __restrict__ dis,
                                                   const float* __restrict__ b1,
                                                   const float* __restrict__ W2,
                                                   float* __restrict__ g2p,
                                                   int bi0) {
    __shared__ float w2s[32 * 16];      // this slice's W2 rows (2 KB)
    __shared__ float rbuf[4][16][36];   // per wave/group r vector (32 feats + pad)
    int tid = threadIdx.x;
    int bi = blockIdx.x + bi0;
    int bucket = bi >> 4;               // 196
    int xcd = bi & 7;
    int slice = xcd >> 1;               // XCD pair {2s,2s+1} -> slice s
    int quarter = ((bi >> 3) & 1) * 2 + (xcd & 1);

    for (int i = tid; i < 512; i += 256) w2s[i] = W2[slice * 512 + i];
    __syncthreads();

    int wave = tid >> 6, lane = tid & 63;
    int g = lane >> 2, m4 = lane & 3;   // group g owns a node; lane m4 covers feats 8*m4..8*m4+7
    const uint4* plane = g1 + (size_t)slice * (N_NODES * 4);
    float* gp = g2p + (size_t)slice * ((size_t)N_NODES * 16);
    int node = bucket * 256 + quarter * 64 + wave * 16 + g;
    bool alive = (node < N_NODES);

#define ACC8(u) do { a0 += bflo((u).x); a1 += bfhi((u).x); a2 += bflo((u).y); a3 += bfhi((u).y); \
                     a4 += bflo((u).z); a5 += bfhi((u).z); a6 += bflo((u).w); a7 += bfhi((u).w); } while (0)
#define GATH(IV, U0, U1, U2, U3) do {                       \
        int j0_ = (int)((IV).x & 0xffffu);                  \
        int j1_ = (int)((IV).x >> 16);                      \
        int j2_ = (int)((IV).y & 0xffffu);                  \
        int j3_ = (int)((IV).y >> 16);                      \
        U0 = plane[(size_t)j0_ * 4 + m4];                   \
        U1 = plane[(size_t)j1_ * 4 + m4];                   \
        U2 = plane[(size_t)j2_ * 4 + m4];                   \
        U3 = plane[(size_t)j3_ * 4 + m4];                   \
    } while (0)

    if (alive) {
        uint4 su = plane[(size_t)node * 4 + m4];   // self loop (g1 carries dis[src])
        float a0 = bflo(su.x), a1 = bfhi(su.x), a2 = bflo(su.y), a3 = bfhi(su.y);
        float a4 = bflo(su.z), a5 = bfhi(su.z), a6 = bflo(su.w), a7 = bfhi(su.w);
        int e = rs[node], e1v = re[node];
        // peel to 4-edge alignment so uint2 index loads are 8B-aligned
        while ((e & 3) && e < e1v) {
            int j = csr_src[e];
            uint4 u = plane[(size_t)j * 4 + m4];
            ACC8(u);
            ++e;
        }
        int nb = (e1v - e) >> 2;   // full batches of 4
        if (nb >= 2) {
            uint2 Ia = *(const uint2*)&csr_src[e];
            uint2 Ib = *(const uint2*)&csr_src[e + 4];
            uint4 A0, A1, A2, A3, B0, B1, B2, B3;
            GATH(Ia, A0, A1, A2, A3);
            GATH(Ib, B0, B1, B2, B3);
            __builtin_amdgcn_sched_barrier(0);
            int b = 2;
            while (b + 2 <= nb) {
                Ia = *(const uint2*)&csr_src[e + 4 * b];      // idx for next A, early
                ACC8(A0); ACC8(A1); ACC8(A2); ACC8(A3);       // consume A (hides Ia)
                GATH(Ia, A0, A1, A2, A3);                     // reissue A
                __builtin_amdgcn_sched_barrier(0);
                Ib = *(const uint2*)&csr_src[e + 4 * b + 4];  // idx for next B, early
                ACC8(B0); ACC8(B1); ACC8(B2); ACC8(B3);       // consume B (hides Ib)
                GATH(Ib, B0, B1, B2, B3);                     // reissue B
                __builtin_amdgcn_sched_barrier(0);
                b += 2;
            }
            int rem = nb - b;   // 0 or 1
            ACC8(A0); ACC8(A1); ACC8(A2); ACC8(A3);
            if (rem) {
                Ia = *(const uint2*)&csr_src[e + 4 * b];
                GATH(Ia, A0, A1, A2, A3);
            }
            ACC8(B0); ACC8(B1); ACC8(B2); ACC8(B3);
            if (rem) { ACC8(A0); ACC8(A1); ACC8(A2); ACC8(A3); }
            e += 4 * nb;
        } else if (nb >= 1) {
            uint2 Iv = *(const uint2*)&csr_src[e];
            uint4 U0, U1, U2, U3;
            GATH(Iv, U0, U1, U2, U3);
            ACC8(U0); ACC8(U1); ACC8(U2); ACC8(U3);
            e += 4;
        }
        while (e < e1v) {   // tail 0..3 edges
            int j = csr_src[e];
            uint4 u = plane[(size_t)j * 4 + m4];
            ACC8(u);
            ++e;
        }

        // bias + ReLU, publish r (lane owns feats 8*m4..8*m4+7)
        float dv = dis[node];
        float4 bb0 = *(const float4*)&b1[slice * 32 + 8 * m4];
        float4 bb1 = *(const float4*)&b1[slice * 32 + 8 * m4 + 4];
        float4 r0, r1;
        r0.x = fmaxf(fmaf(dv, a0, bb0.x), 0.f);
        r0.y = fmaxf(fmaf(dv, a1, bb0.y), 0.f);
        r0.z = fmaxf(fmaf(dv, a2, bb0.z), 0.f);
        r0.w = fmaxf(fmaf(dv, a3, bb0.w), 0.f);
        r1.x = fmaxf(fmaf(dv, a4, bb1.x), 0.f);
        r1.y = fmaxf(fmaf(dv, a5, bb1.y), 0.f);
        r1.z = fmaxf(fmaf(dv, a6, bb1.z), 0.f);
        r1.w = fmaxf(fmaf(dv, a7, bb1.w), 0.f);
        *(float4*)&rbuf[wave][g][8 * m4] = r0;
        *(float4*)&rbuf[wave][g][8 * m4 + 4] = r1;
    }
    __builtin_amdgcn_sched_barrier(0);   // wave-synchronous LDS: keep reads after writes
    if (alive) {
        // GEMM2 partial: lane m4 computes classes 4*m4..4*m4+3 over all 32 feats
        float p0 = 0.f, p1 = 0.f, p2 = 0.f, p3 = 0.f;
#pragma unroll
        for (int fb = 0; fb < 8; ++fb) {
            float4 rv = *(const float4*)&rbuf[wave][g][fb * 4];
            float4 w0 = *(const float4*)&w2s[(fb * 4 + 0) * 16 + 4 * m4];
            float4 w1 = *(const float4*)&w2s[(fb * 4 + 1) * 16 + 4 * m4];
            float4 w2 = *(const float4*)&w2s[(fb * 4 + 2) * 16 + 4 * m4];
            float4 w3 = *(const float4*)&w2s[(fb * 4 + 3) * 16 + 4 * m4];
            p0 = fmaf(rv.x, w0.x, p0); p1 = fmaf(rv.x, w0.y, p1);
            p2 = fmaf(rv.x, w0.z, p2); p3 = fmaf(rv.x, w0.w, p3);
            p0 = fmaf(rv.y, w1.x, p0); p1 = fmaf(rv.y, w1.y, p1);
            p2 = fmaf(rv.y, w1.z, p2); p3 = fmaf(rv.y, w1.w, p3);
            p0 = fmaf(rv.z, w2.x, p0); p1 = fmaf(rv.z, w2.y, p1);
            p2 = fmaf(rv.z, w2.z, p2); p3 = fmaf(rv.z, w2.w, p3);
            p0 = fmaf(rv.w, w3.x, p0); p1 = fmaf(rv.w, w3.y, p1);
            p2 = fmaf(rv.w, w3.z, p2); p3 = fmaf(rv.w, w3.w, p3);
        }
        float4 pv; pv.x = p0; pv.y = p1; pv.z = p2; pv.w = p3;
        *(float4*)&gp[(size_t)node * 16 + 4 * m4] = pv;
    }
#undef GATH
#undef ACC8
}

// ---------------------------------------------------------------------------
// Combine the 4 per-slice GEMM2 partials + dis scale, in place into plane 0.
// ---------------------------------------------------------------------------
__global__ __launch_bounds__(256) void g2_reduce(float* __restrict__ g2p,
                                                 const float* __restrict__ dis) {
    int i = blockIdx.x * 256 + threadIdx.x;   // one float4 (4 classes)
    if (i >= N_NODES * 4) return;
    const size_t PS = (size_t)N_NODES * 16 / 4;  // plane stride in float4
    const float4* p = (const float4*)g2p;
    float4 a = p[i];
    float4 b = p[i + PS];
    float4 c = p[i + 2 * PS];
    float4 d = p[i + 3 * PS];
    float dv = dis[i >> 2];
    float4 r;
    r.x = dv * ((a.x + b.x) + (c.x + d.x));
    r.y = dv * ((a.y + b.y) + (c.y + d.y));
    r.z = dv * ((a.z + b.z) + (c.z + d.z));
    r.w = dv * ((a.w + b.w) + (c.w + d.w));
    ((float4*)g2p)[i] = r;
}

// ---------------------------------------------------------------------------
// Aggregation 2 + bias + logits + softmax. Depth-2 ping-pong with direct
// uint2 index loads. g2 (3.2 MB) is L2-resident per XCD by size.
// ---------------------------------------------------------------------------
__global__ __launch_bounds__(256) void agg2_softmax(const float4* __restrict__ g2,
                                                    const int* __restrict__ rs,
                                                    const int* __restrict__ re,
                                                    const unsigned short* __restrict__ csr_src,
                                                    const float* __restrict__ dis,
                                                    const float* __restrict__ b2,
                                                    float* __restrict__ out) {
    int tid = threadIdx.x;
    int wave = tid >> 6, lane = tid & 63;
    int g = lane >> 2, m4 = lane & 3;   // group owns a node; lane m4 covers classes 4*m4..4*m4+3
    int node = blockIdx.x * 64 + wave * 16 + g;
    if (node >= N_NODES) return;

    float4 acc = g2[(size_t)node * 4 + m4];   // self loop

#define ACC4(u) do { acc.x += (u).x; acc.y += (u).y; acc.z += (u).z; acc.w += (u).w; } while (0)
#define GATH4(IV, U0, U1, U2, U3) do {                      \
        int j0_ = (int)((IV).x & 0xffffu);                  \
        int j1_ = (int)((IV).x >> 16);                      \
        int j2_ = (int)((IV).y & 0xffffu);                  \
        int j3_ = (int)((IV).y >> 16);                      \
        U0 = g2[(size_t)j0_ * 4 + m4];                      \
        U1 = g2[(size_t)j1_ * 4 + m4];                      \
        U2 = g2[(size_t)j2_ * 4 + m4];                      \
        U3 = g2[(size_t)j3_ * 4 + m4];                      \
    } while (0)

    int e = rs[node], e1v = re[node];
    while ((e & 3) && e < e1v) {
        int j = csr_src[e];
        float4 u = g2[(size_t)j * 4 + m4];
        ACC4(u);
        ++e;
    }
    int nb = (e1v - e) >> 2;
    if (nb >= 2) {
        uint2 Ia = *(const uint2*)&csr_src[e];
        uint2 Ib = *(const uint2*)&csr_src[e + 4];
        float4 A0, A1, A2, A3, B0, B1, B2, B3;
        GATH4(Ia, A0, A1, A2, A3);
        GATH4(Ib, B0, B1, B2, B3);
        __builtin_amdgcn_sched_barrier(0);
        int b = 2;
        while (b + 2 <= nb) {
            Ia = *(const uint2*)&csr_src[e + 4 * b];
            ACC4(A0); ACC4(A1); ACC4(A2); ACC4(A3);
            GATH4(Ia, A0, A1, A2, A3);
            __builtin_amdgcn_sched_barrier(0);
            Ib = *(const uint2*)&csr_src[e + 4 * b + 4];
            ACC4(B0); ACC4(B1); ACC4(B2); ACC4(B3);
            GATH4(Ib, B0, B1, B2, B3);
            __builtin_amdgcn_sched_barrier(0);
            b += 2;
        }
        int rem = nb - b;
        ACC4(A0); ACC4(A1); ACC4(A2); ACC4(A3);
        if (rem) {
            Ia = *(const uint2*)&csr_src[e + 4 * b];
            GATH4(Ia, A0, A1, A2, A3);
        }
        ACC4(B0); ACC4(B1); ACC4(B2); ACC4(B3);
        if (rem) { ACC4(A0); ACC4(A1); ACC4(A2); ACC4(A3); }
        e += 4 * nb;
    } else if (nb >= 1) {
        uint2 Iv = *(const uint2*)&csr_src[e];
        float4 U0, U1, U2, U3;
        GATH4(Iv, U0, U1, U2, U3);
        ACC4(U0); ACC4(U1); ACC4(U2); ACC4(U3);
        e += 4;
    }
    while (e < e1v) {
        int j = csr_src[e];
        float4 u = g2[(size_t)j * 4 + m4];
        ACC4(u);
        ++e;
    }
#undef GATH4
#undef ACC4

    float dv = dis[node];
    float4 bb = *(const float4*)&b2[4 * m4];
    float4 lg;
    lg.x = fmaf(dv, acc.x, bb.x);
    lg.y = fmaf(dv, acc.y, bb.y);
    lg.z = fmaf(dv, acc.z, bb.z);
    lg.w = fmaf(dv, acc.w, bb.w);
    ((float4*)out)[(size_t)node * 4 + m4] = lg;

    // softmax over 16 classes = 4 lanes x 4
    float m = fmaxf(fmaxf(lg.x, lg.y), fmaxf(lg.z, lg.w));
    m = fmaxf(m, __shfl_xor(m, 1));
    m = fmaxf(m, __shfl_xor(m, 2));
    float4 ex;
    ex.x = expf(lg.x - m); ex.y = expf(lg.y - m);
    ex.z = expf(lg.z - m); ex.w = expf(lg.w - m);
    float s = (ex.x + ex.y) + (ex.z + ex.w);
    s += __shfl_xor(s, 1);
    s += __shfl_xor(s, 2);
    float inv = 1.0f / s;
    ex.x *= inv; ex.y *= inv; ex.z *= inv; ex.w *= inv;
    ((float4*)out)[(size_t)N_NODES * 4 + (size_t)node * 4 + m4] = ex;
}

// ---------------------------------------------------------------------------

extern "C" void kernel_launch(void* const* d_in, const int* in_sizes, int n_in,
                              void* d_out, int out_size, void* d_ws, size_t ws_size,
                              hipStream_t stream) {
    const float* x  = (const float*)d_in[0];
    const int*   ei = (const int*)d_in[1];
    const float* W1 = (const float*)d_in[2];
    const float* b1 = (const float*)d_in[3];
    const float* W2 = (const float*)d_in[4];
    const float* b2 = (const float*)d_in[5];
    float* out = (float*)d_out;

    char* ws = (char*)d_ws;
    size_t off = 0;
    auto alloc = [&](size_t bytes) -> char* {
        char* p = ws + off;
        off = (off + bytes + 511) & ~(size_t)511;
        return p;
    };
    int*   cursor   = (int*)alloc(256 * CSTR * 4);
    float* dis      = (float*)alloc(N_NODES * 4);
    int*   rs       = (int*)alloc(N_NODES * 4);
    int*   re       = (int*)alloc(N_NODES * 4);
    unsigned short* w1t = (unsigned short*)alloc((size_t)HIDDEN * IN_FEAT * 2);
    unsigned short* csr_src = (unsigned short*)alloc((size_t)NBKT * BCAP * 2);  // holey
    unsigned int* g1 = (unsigned int*)alloc((size_t)N_NODES * 64 * 4);          // slice-major: 4 x [N][16dw]
    float* g2p      = (float*)alloc(4 * (size_t)N_NODES * N_CLASSES * 4);       // per-slice GEMM2 partials
    // sorted edges (196*10240*4 = 8.0MB) alias g1's slab (12.8MB): dead before gemm1.
    unsigned int* sorted = (unsigned int*)g1;
    (void)ws_size; (void)in_sizes; (void)n_in; (void)out_size;

    const int* src = ei;
    const int* dst = ei + N_EDGES;

    hipMemsetAsync(cursor, 0, 256 * CSTR * 4, stream);
    scatter_edges2<<<NCHK, 256, 0, stream>>>(src, dst, cursor, sorted, W1, w1t);
    build_csr2<<<NBKT, 512, 0, stream>>>(sorted, cursor, rs, re, dis, csr_src);

    gemm1_mfma<<<(N_NODES + 31) / 32, 256, 0, stream>>>(x, w1t, dis, g1);
    // agg1 split into two half-grid dispatches (diagnostic: drops instance
    // dur to ~26us so any hidden >28us kernel surfaces in the top-5 table)
    agg1_sliced<<<NBKT * 8, 256, 0, stream>>>((const uint4*)g1, rs, re, csr_src, dis, b1, W2, g2p, 0);
    agg1_sliced<<<NBKT * 8, 256, 0, stream>>>((const uint4*)g1, rs, re, csr_src, dis, b1, W2, g2p, NBKT * 8);
    g2_reduce<<<(N_NODES * 4 + 255) / 256, 256, 0, stream>>>(g2p, dis);
    agg2_softmax<<<N_NODES / 64 + 1, 256, 0, stream>>>((const float4*)g2p, rs, re, csr_src, dis, b2, out);
}

// Round 9
// 223.373 us; speedup vs baseline: 1.0641x; 1.0304x over previous
//
#include <hip/hip_runtime.h>
#include <hip/hip_bf16.h>
#include <math.h>

#define N_NODES 50000
#define N_EDGES 1600000
#define IN_FEAT 256
#define HIDDEN 128
#define N_CLASSES 16

#define ECHUNK 2048
#define NCHK 782    // ceil(1600000/2048)
#define NBKT 196    // ceil(50000/256) buckets of 256 nodes
#define BCAP 10240  // per-bucket capacity: mean 8192, std ~90 -> +23 sigma
#define CSTR 16     // cursor stride (ints): 1 counter per 64B line

typedef __attribute__((ext_vector_type(8))) short short8;   // 8 bf16 (A/B frag)
typedef __attribute__((ext_vector_type(4))) float floatx4;  // C/D frag

// bf16 round-to-nearest-even (scalar integer path)
__device__ __forceinline__ unsigned short f2bf(float f) {
    unsigned u = __float_as_uint(f);
    return (unsigned short)((u + 0x7fffu + ((u >> 16) & 1u)) >> 16);
}

// HW packed fp32->bf16x2
__device__ __forceinline__ unsigned pk2bf(float a, float b) {
    __hip_bfloat162 h = __float22bfloat162_rn(make_float2(a, b));
    union { __hip_bfloat162 h; unsigned u; } cv;
    cv.h = h;
    return cv.u;
}

__device__ __forceinline__ float bflo(unsigned u) { return __uint_as_float(u << 16); }
__device__ __forceinline__ float bfhi(unsigned u) { return __uint_as_float(u & 0xffff0000u); }

// ---------------------------------------------------------------------------
// Prep: fixed-capacity buckets. 782 blocks (2048 edges each); cursor
// counters padded to 1/line. Blocks 0..127 transpose W1 -> w1t.
// ---------------------------------------------------------------------------
__global__ __launch_bounds__(256) void scatter_edges2(const int* __restrict__ src,
                                                      const int* __restrict__ dst,
                                                      int* __restrict__ cursor,   // [256*CSTR], zeroed
                                                      unsigned int* __restrict__ sorted,
                                                      const float* __restrict__ W1,
                                                      unsigned short* __restrict__ w1t) {
    __shared__ int hloc[256];
    int t = threadIdx.x;
    hloc[t] = 0;
    if (blockIdx.x < HIDDEN)
        w1t[blockIdx.x * IN_FEAT + t] = f2bf(W1[t * HIDDEN + blockIdx.x]);
    __syncthreads();
    int base = blockIdx.x * ECHUNK;
    int end = min(base + ECHUNK, N_EDGES);
    for (int i = base + t; i < end; i += 256)
        atomicAdd(&hloc[dst[i] >> 8], 1);
    __syncthreads();
    int cnt = hloc[t];
    int lbase = 0;
    if (cnt > 0) lbase = t * BCAP + atomicAdd(&cursor[t * CSTR], cnt);  // block's base in bucket t
    __syncthreads();
    hloc[t] = lbase;  // reuse as local cursor
    __syncthreads();
    for (int i = base + t; i < end; i += 256) {
        int d = dst[i];
        int s = src[i];
        int pos = atomicAdd(&hloc[d >> 8], 1);
        sorted[pos] = ((unsigned)d << 16) | (unsigned)s;
    }
}

// 512 threads/block -> 16 edges/thread serial passes.
__global__ __launch_bounds__(512) void build_csr2(const unsigned int* __restrict__ sorted,
                                                  const int* __restrict__ cursor,
                                                  int* __restrict__ rs,
                                                  int* __restrict__ re,
                                                  float* __restrict__ dis,
                                                  unsigned short* __restrict__ csr_src) {
    __shared__ int cnt[256];
    __shared__ int roff[256];
    int t = threadIdx.x;      // 0..511
    int bkt = blockIdx.x;
    int ebase = bkt * BCAP;
    int eend = ebase + cursor[bkt * CSTR];
    if (t < 256) cnt[t] = 0;
    __syncthreads();
    for (int i = ebase + t; i < eend; i += 512)
        atomicAdd(&cnt[(sorted[i] >> 16) & 255], 1);
    __syncthreads();
    int v = 0;
    if (t < 256) { v = cnt[t]; roff[t] = v; }
    __syncthreads();
    for (int off = 1; off < 256; off <<= 1) {
        int x = (t < 256 && t >= off) ? roff[t - off] : 0;
        __syncthreads();
        if (t < 256) roff[t] += x;
        __syncthreads();
    }
    if (t < 256) {
        int excl = roff[t] - v;
        int node = bkt * 256 + t;
        if (node < N_NODES) {
            rs[node] = ebase + excl;
            re[node] = ebase + excl + v;
            dis[node] = 1.0f / sqrtf((float)(v + 1));  // +1 self loop
        }
        cnt[t] = ebase + excl;  // reuse as cursor
    }
    __syncthreads();
    for (int i = ebase + t; i < eend; i += 512) {
        unsigned e = sorted[i];
        int pos = atomicAdd(&cnt[(e >> 16) & 255], 1);
        csr_src[pos] = (unsigned short)(e & 0xffffu);
    }
}

// ---------------------------------------------------------------------------
// GEMM1 (v7 structure kept): 32-row x 128-col block, whole 32x256 x-panel
// staged up front, ONE barrier, 8 barrier-free K-steps. v9: output layout
// changed to TWO 64-feature slice planes (6.4 MB each): plane = col>>6,
// node stride 32 dwords, dword = (col&63)>>1.
// ---------------------------------------------------------------------------
#define XCHDW 260   // dwords per 8-row chunk: 8*32 + 4 pad
#define KBLK (4 * XCHDW)   // dwords per kk block (4 chunks = 32 rows)

__global__ __launch_bounds__(256) void gemm1_mfma(const float* __restrict__ x,
                                                  const unsigned short* __restrict__ w1t,
                                                  const float* __restrict__ dis,
                                                  unsigned int* __restrict__ g1) {
    __shared__ float xs[8 * KBLK];   // 33,280 B
    int tid = threadIdx.x;
    int w = tid >> 6;
    int lane = tid & 63;
    int quad = lane >> 4;
    int c = lane & 15;
    int row_base = blockIdx.x * 32;
    int col_base = w * 32;

    // staging: wave w stages rows row_base+8w .. +8w+7, all K (8 issues)
    int st_row = min(row_base + 8 * w + (lane >> 3), N_NODES - 1);
    const float* gp1 = x + (size_t)st_row * IN_FEAT + (lane & 7) * 4;
#pragma unroll
    for (int kk = 0; kk < 8; ++kk)
        __builtin_amdgcn_global_load_lds(
            (const __attribute__((address_space(1))) void*)(gp1 + kk * 32),
            (__attribute__((address_space(3))) void*)&xs[kk * KBLK + w * XCHDW], 16, 0, 0);

    floatx4 acc[2][2] = {};
    const unsigned short* bp[2];
#pragma unroll
    for (int nt = 0; nt < 2; ++nt)
        bp[nt] = w1t + (size_t)(col_base + nt * 16 + c) * IN_FEAT + quad * 8;

    int dwoff[2];
#pragma unroll
    for (int rt = 0; rt < 2; ++rt) {
        int rit = rt * 16 + c;
        dwoff[rt] = (rit >> 3) * XCHDW + (rit & 7) * 32 + quad * 8;
    }

    __syncthreads();   // single drain: all 32 stage issues

#pragma unroll
    for (int kk = 0; kk < 8; ++kk) {
        short8 b[2];
#pragma unroll
        for (int nt = 0; nt < 2; ++nt)
            b[nt] = *(const short8*)(bp[nt] + kk * 32);
        short8 a[2];
#pragma unroll
        for (int rt = 0; rt < 2; ++rt) {
            float4 f0 = *(const float4*)&xs[kk * KBLK + dwoff[rt]];
            float4 f1 = *(const float4*)&xs[kk * KBLK + dwoff[rt] + 4];
            union { short8 s; unsigned u[4]; } au;
            au.u[0] = pk2bf(f0.x, f0.y);
            au.u[1] = pk2bf(f0.z, f0.w);
            au.u[2] = pk2bf(f1.x, f1.y);
            au.u[3] = pk2bf(f1.z, f1.w);
            a[rt] = au.s;
        }
#pragma unroll
        for (int rt = 0; rt < 2; ++rt)
#pragma unroll
            for (int nt = 0; nt < 2; ++nt)
                acc[rt][nt] = __builtin_amdgcn_mfma_f32_16x16x32_bf16(a[rt], b[nt], acc[rt][nt], 0, 0, 0);
    }

    // Epilogue: dis scale, pair adjacent cols via shfl, pack bf16x2, store
    // into 2-slice layout. C/D layout: col = lane&15, row = quad*4 + reg.
    bool evenlane = (lane & 1) == 0;
#pragma unroll
    for (int rt = 0; rt < 2; ++rt) {
#pragma unroll
        for (int reg = 0; reg < 4; ++reg) {
            int row = row_base + rt * 16 + quad * 4 + reg;
            float dv = dis[min(row, N_NODES - 1)];
#pragma unroll
            for (int nt = 0; nt < 2; ++nt) {
                float v = acc[rt][nt][reg] * dv;
                float vo = __shfl_xor(v, 1);
                if (evenlane && row < N_NODES) {
                    unsigned pkd = (unsigned)f2bf(v) | ((unsigned)f2bf(vo) << 16);
                    int col = col_base + nt * 16 + c;  // even
                    g1[(size_t)(col >> 6) * ((size_t)N_NODES * 32) + (size_t)row * 32 + ((col & 63) >> 1)] = pkd;
                }
            }
        }
    }
}

// ---------------------------------------------------------------------------
// Aggregation 1 + bias + ReLU + per-slice GEMM2 partial.
// v9: TWO slices of 64 feats (128 B/node/slice) -> one full 128-B line per
// edge-visit: 3.2M line visits total vs v8's 6.4M (same bytes). Tests the
// "L2 request-rate wall" hypothesis. Plane = 6.4 MB on 4 MB XCD L2 (~62%
// hit; misses L3-resident). XCDs 0-3 -> slice 0, 4-7 -> slice 1. 8-lane
// groups, depth-2 ping-pong, direct uint2 index loads (proven structure).
// ---------------------------------------------------------------------------
__global__ __launch_bounds__(256) void agg1_sliced(const uint4* __restrict__ g1,
                                                   const int* __restrict__ rs,
                                                   const int* __restrict__ re,
                                                   const unsigned short* __restrict__ csr_src,
                                                   const float* __restrict__ dis,
                                                   const float* __restrict__ b1,
                                                   const float* __restrict__ W2,
                                                   float* __restrict__ g2p) {
    __shared__ float w2s[64 * 16];      // this slice's W2 rows (4 KB)
    __shared__ float rbuf[4][8][68];    // per wave/group r vector (64 feats + pad)
    int tid = threadIdx.x;
    int bi = blockIdx.x;
    int bucket = bi >> 4;               // 196
    int xcd = bi & 7;
    int slice = xcd >> 2;               // XCDs 0-3 -> slice 0, 4-7 -> slice 1
    int sub = ((bi >> 3) & 1) * 4 + (xcd & 3);   // 0..7: 32-node sub-block

    for (int i = tid; i < 1024; i += 256) w2s[i] = W2[slice * 1024 + i];
    __syncthreads();

    int wave = tid >> 6, lane = tid & 63;
    int g = lane >> 3, m = lane & 7;    // group g owns a node; lane m covers feats 8m..8m+7
    const uint4* plane = g1 + (size_t)slice * ((size_t)N_NODES * 8);
    float* gp = g2p + (size_t)slice * ((size_t)N_NODES * 16);
    int node = bucket * 256 + sub * 32 + wave * 8 + g;
    bool alive = (node < N_NODES);

#define ACC8(u) do { a0 += bflo((u).x); a1 += bfhi((u).x); a2 += bflo((u).y); a3 += bfhi((u).y); \
                     a4 += bflo((u).z); a5 += bfhi((u).z); a6 += bflo((u).w); a7 += bfhi((u).w); } while (0)
#define GATH(IV, U0, U1, U2, U3) do {                       \
        int j0_ = (int)((IV).x & 0xffffu);                  \
        int j1_ = (int)((IV).x >> 16);                      \
        int j2_ = (int)((IV).y & 0xffffu);                  \
        int j3_ = (int)((IV).y >> 16);                      \
        U0 = plane[(size_t)j0_ * 8 + m];                    \
        U1 = plane[(size_t)j1_ * 8 + m];                    \
        U2 = plane[(size_t)j2_ * 8 + m];                    \
        U3 = plane[(size_t)j3_ * 8 + m];                    \
    } while (0)

    if (alive) {
        uint4 su = plane[(size_t)node * 8 + m];   // self loop (g1 carries dis[src])
        float a0 = bflo(su.x), a1 = bfhi(su.x), a2 = bflo(su.y), a3 = bfhi(su.y);
        float a4 = bflo(su.z), a5 = bfhi(su.z), a6 = bflo(su.w), a7 = bfhi(su.w);
        int e = rs[node], e1v = re[node];
        // peel to 4-edge alignment so uint2 index loads are 8B-aligned
        while ((e & 3) && e < e1v) {
            int j = csr_src[e];
            uint4 u = plane[(size_t)j * 8 + m];
            ACC8(u);
            ++e;
        }
        int nb = (e1v - e) >> 2;   // full batches of 4
        if (nb >= 2) {
            uint2 Ia = *(const uint2*)&csr_src[e];
            uint2 Ib = *(const uint2*)&csr_src[e + 4];
            uint4 A0, A1, A2, A3, B0, B1, B2, B3;
            GATH(Ia, A0, A1, A2, A3);
            GATH(Ib, B0, B1, B2, B3);
            __builtin_amdgcn_sched_barrier(0);
            int b = 2;
            while (b + 2 <= nb) {
                Ia = *(const uint2*)&csr_src[e + 4 * b];      // idx for next A, early
                ACC8(A0); ACC8(A1); ACC8(A2); ACC8(A3);       // consume A (hides Ia)
                GATH(Ia, A0, A1, A2, A3);                     // reissue A
                __builtin_amdgcn_sched_barrier(0);
                Ib = *(const uint2*)&csr_src[e + 4 * b + 4];  // idx for next B, early
                ACC8(B0); ACC8(B1); ACC8(B2); ACC8(B3);       // consume B (hides Ib)
                GATH(Ib, B0, B1, B2, B3);                     // reissue B
                __builtin_amdgcn_sched_barrier(0);
                b += 2;
            }
            int rem = nb - b;   // 0 or 1
            ACC8(A0); ACC8(A1); ACC8(A2); ACC8(A3);
            if (rem) {
                Ia = *(const uint2*)&csr_src[e + 4 * b];
                GATH(Ia, A0, A1, A2, A3);
            }
            ACC8(B0); ACC8(B1); ACC8(B2); ACC8(B3);
            if (rem) { ACC8(A0); ACC8(A1); ACC8(A2); ACC8(A3); }
            e += 4 * nb;
        } else if (nb >= 1) {
            uint2 Iv = *(const uint2*)&csr_src[e];
            uint4 U0, U1, U2, U3;
            GATH(Iv, U0, U1, U2, U3);
            ACC8(U0); ACC8(U1); ACC8(U2); ACC8(U3);
            e += 4;
        }
        while (e < e1v) {   // tail 0..3 edges
            int j = csr_src[e];
            uint4 u = plane[(size_t)j * 8 + m];
            ACC8(u);
            ++e;
        }

        // bias + ReLU, publish r (lane owns feats 8m..8m+7 of this slice)
        float dv = dis[node];
        float4 bb0 = *(const float4*)&b1[slice * 64 + 8 * m];
        float4 bb1 = *(const float4*)&b1[slice * 64 + 8 * m + 4];
        float4 r0, r1;
        r0.x = fmaxf(fmaf(dv, a0, bb0.x), 0.f);
        r0.y = fmaxf(fmaf(dv, a1, bb0.y), 0.f);
        r0.z = fmaxf(fmaf(dv, a2, bb0.z), 0.f);
        r0.w = fmaxf(fmaf(dv, a3, bb0.w), 0.f);
        r1.x = fmaxf(fmaf(dv, a4, bb1.x), 0.f);
        r1.y = fmaxf(fmaf(dv, a5, bb1.y), 0.f);
        r1.z = fmaxf(fmaf(dv, a6, bb1.z), 0.f);
        r1.w = fmaxf(fmaf(dv, a7, bb1.w), 0.f);
        *(float4*)&rbuf[wave][g][8 * m] = r0;
        *(float4*)&rbuf[wave][g][8 * m + 4] = r1;
    }
    __builtin_amdgcn_sched_barrier(0);   // wave-synchronous LDS: keep reads after writes
    if (alive) {
        // GEMM2 partial: lane m computes classes 2m, 2m+1 over 64 slice feats
        float p0 = 0.f, p1 = 0.f;
#pragma unroll
        for (int fb = 0; fb < 16; ++fb) {
            float4 rv = *(const float4*)&rbuf[wave][g][fb * 4];
            p0 = fmaf(rv.x, w2s[(fb * 4 + 0) * 16 + 2 * m], p0);
            p1 = fmaf(rv.x, w2s[(fb * 4 + 0) * 16 + 2 * m + 1], p1);
            p0 = fmaf(rv.y, w2s[(fb * 4 + 1) * 16 + 2 * m], p0);
            p1 = fmaf(rv.y, w2s[(fb * 4 + 1) * 16 + 2 * m + 1], p1);
            p0 = fmaf(rv.z, w2s[(fb * 4 + 2) * 16 + 2 * m], p0);
            p1 = fmaf(rv.z, w2s[(fb * 4 + 2) * 16 + 2 * m + 1], p1);
            p0 = fmaf(rv.w, w2s[(fb * 4 + 3) * 16 + 2 * m], p0);
            p1 = fmaf(rv.w, w2s[(fb * 4 + 3) * 16 + 2 * m + 1], p1);
        }
        *(float2*)&gp[(size_t)node * 16 + 2 * m] = make_float2(p0, p1);
    }
#undef GATH
#undef ACC8
}

// ---------------------------------------------------------------------------
// Combine the 2 per-slice GEMM2 partials + dis scale, in place into plane 0.
// ---------------------------------------------------------------------------
__global__ __launch_bounds__(256) void g2_reduce(float* __restrict__ g2p,
                                                 const float* __restrict__ dis) {
    int i = blockIdx.x * 256 + threadIdx.x;   // one float4 (4 classes)
    if (i >= N_NODES * 4) return;
    const size_t PS = (size_t)N_NODES * 16 / 4;  // plane stride in float4
    const float4* p = (const float4*)g2p;
    float4 a = p[i];
    float4 b = p[i + PS];
    float dv = dis[i >> 2];
    float4 r;
    r.x = dv * (a.x + b.x);
    r.y = dv * (a.y + b.y);
    r.z = dv * (a.z + b.z);
    r.w = dv * (a.w + b.w);
    ((float4*)g2p)[i] = r;
}

// ---------------------------------------------------------------------------
// Aggregation 2 + bias + logits + softmax. Depth-2 ping-pong with direct
// uint2 index loads. g2 (3.2 MB) is L2-resident per XCD by size.
// ---------------------------------------------------------------------------
__global__ __launch_bounds__(256) void agg2_softmax(const float4* __restrict__ g2,
                                                    const int* __restrict__ rs,
                                                    const int* __restrict__ re,
                                                    const unsigned short* __restrict__ csr_src,
                                                    const float* __restrict__ dis,
                                                    const float* __restrict__ b2,
                                                    float* __restrict__ out) {
    int tid = threadIdx.x;
    int wave = tid >> 6, lane = tid & 63;
    int g = lane >> 2, m4 = lane & 3;   // group owns a node; lane m4 covers classes 4*m4..4*m4+3
    int node = blockIdx.x * 64 + wave * 16 + g;
    if (node >= N_NODES) return;

    float4 acc = g2[(size_t)node * 4 + m4];   // self loop

#define ACC4(u) do { acc.x += (u).x; acc.y += (u).y; acc.z += (u).z; acc.w += (u).w; } while (0)
#define GATH4(IV, U0, U1, U2, U3) do {                      \
        int j0_ = (int)((IV).x & 0xffffu);                  \
        int j1_ = (int)((IV).x >> 16);                      \
        int j2_ = (int)((IV).y & 0xffffu);                  \
        int j3_ = (int)((IV).y >> 16);                      \
        U0 = g2[(size_t)j0_ * 4 + m4];                      \
        U1 = g2[(size_t)j1_ * 4 + m4];                      \
        U2 = g2[(size_t)j2_ * 4 + m4];                      \
        U3 = g2[(size_t)j3_ * 4 + m4];                      \
    } while (0)

    int e = rs[node], e1v = re[node];
    while ((e & 3) && e < e1v) {
        int j = csr_src[e];
        float4 u = g2[(size_t)j * 4 + m4];
        ACC4(u);
        ++e;
    }
    int nb = (e1v - e) >> 2;
    if (nb >= 2) {
        uint2 Ia = *(const uint2*)&csr_src[e];
        uint2 Ib = *(const uint2*)&csr_src[e + 4];
        float4 A0, A1, A2, A3, B0, B1, B2, B3;
        GATH4(Ia, A0, A1, A2, A3);
        GATH4(Ib, B0, B1, B2, B3);
        __builtin_amdgcn_sched_barrier(0);
        int b = 2;
        while (b + 2 <= nb) {
            Ia = *(const uint2*)&csr_src[e + 4 * b];
            ACC4(A0); ACC4(A1); ACC4(A2); ACC4(A3);
            GATH4(Ia, A0, A1, A2, A3);
            __builtin_amdgcn_sched_barrier(0);
            Ib = *(const uint2*)&csr_src[e + 4 * b + 4];
            ACC4(B0); ACC4(B1); ACC4(B2); ACC4(B3);
            GATH4(Ib, B0, B1, B2, B3);
            __builtin_amdgcn_sched_barrier(0);
            b += 2;
        }
        int rem = nb - b;
        ACC4(A0); ACC4(A1); ACC4(A2); ACC4(A3);
        if (rem) {
            Ia = *(const uint2*)&csr_src[e + 4 * b];
            GATH4(Ia, A0, A1, A2, A3);
        }
        ACC4(B0); ACC4(B1); ACC4(B2); ACC4(B3);
        if (rem) { ACC4(A0); ACC4(A1); ACC4(A2); ACC4(A3); }
        e += 4 * nb;
    } else if (nb >= 1) {
        uint2 Iv = *(const uint2*)&csr_src[e];
        float4 U0, U1, U2, U3;
        GATH4(Iv, U0, U1, U2, U3);
        ACC4(U0); ACC4(U1); ACC4(U2); ACC4(U3);
        e += 4;
    }
    while (e < e1v) {
        int j = csr_src[e];
        float4 u = g2[(size_t)j * 4 + m4];
        ACC4(u);
        ++e;
    }
#undef GATH4
#undef ACC4

    float dv = dis[node];
    float4 bb = *(const float4*)&b2[4 * m4];
    float4 lg;
    lg.x = fmaf(dv, acc.x, bb.x);
    lg.y = fmaf(dv, acc.y, bb.y);
    lg.z = fmaf(dv, acc.z, bb.z);
    lg.w = fmaf(dv, acc.w, bb.w);
    ((float4*)out)[(size_t)node * 4 + m4] = lg;

    // softmax over 16 classes = 4 lanes x 4
    float m = fmaxf(fmaxf(lg.x, lg.y), fmaxf(lg.z, lg.w));
    m = fmaxf(m, __shfl_xor(m, 1));
    m = fmaxf(m, __shfl_xor(m, 2));
    float4 ex;
    ex.x = expf(lg.x - m); ex.y = expf(lg.y - m);
    ex.z = expf(lg.z - m); ex.w = expf(lg.w - m);
    float s = (ex.x + ex.y) + (ex.z + ex.w);
    s += __shfl_xor(s, 1);
    s += __shfl_xor(s, 2);
    float inv = 1.0f / s;
    ex.x *= inv; ex.y *= inv; ex.z *= inv; ex.w *= inv;
    ((float4*)out)[(size_t)N_NODES * 4 + (size_t)node * 4 + m4] = ex;
}

// ---------------------------------------------------------------------------

extern "C" void kernel_launch(void* const* d_in, const int* in_sizes, int n_in,
                              void* d_out, int out_size, void* d_ws, size_t ws_size,
                              hipStream_t stream) {
    const float* x  = (const float*)d_in[0];
    const int*   ei = (const int*)d_in[1];
    const float* W1 = (const float*)d_in[2];
    const float* b1 = (const float*)d_in[3];
    const float* W2 = (const float*)d_in[4];
    const float* b2 = (const float*)d_in[5];
    float* out = (float*)d_out;

    char* ws = (char*)d_ws;
    size_t off = 0;
    auto alloc = [&](size_t bytes) -> char* {
        char* p = ws + off;
        off = (off + bytes + 511) & ~(size_t)511;
        return p;
    };
    int*   cursor   = (int*)alloc(256 * CSTR * 4);
    float* dis      = (float*)alloc(N_NODES * 4);
    int*   rs       = (int*)alloc(N_NODES * 4);
    int*   re       = (int*)alloc(N_NODES * 4);
    unsigned short* w1t = (unsigned short*)alloc((size_t)HIDDEN * IN_FEAT * 2);
    unsigned short* csr_src = (unsigned short*)alloc((size_t)NBKT * BCAP * 2);  // holey
    unsigned int* g1 = (unsigned int*)alloc((size_t)N_NODES * 64 * 4);          // 2 slice planes of 64 feats
    float* g2p      = (float*)alloc(2 * (size_t)N_NODES * N_CLASSES * 4);       // per-slice GEMM2 partials
    // sorted edges (196*10240*4 = 8.0MB) alias g1's slab (12.8MB): dead before gemm1.
    unsigned int* sorted = (unsigned int*)g1;
    (void)ws_size; (void)in_sizes; (void)n_in; (void)out_size;

    const int* src = ei;
    const int* dst = ei + N_EDGES;

    hipMemsetAsync(cursor, 0, 256 * CSTR * 4, stream);
    scatter_edges2<<<NCHK, 256, 0, stream>>>(src, dst, cursor, sorted, W1, w1t);
    build_csr2<<<NBKT, 512, 0, stream>>>(sorted, cursor, rs, re, dis, csr_src);

    gemm1_mfma<<<(N_NODES + 31) / 32, 256, 0, stream>>>(x, w1t, dis, g1);
    agg1_sliced<<<NBKT * 16, 256, 0, stream>>>((const uint4*)g1, rs, re, csr_src, dis, b1, W2, g2p);
    g2_reduce<<<(N_NODES * 4 + 255) / 256, 256, 0, stream>>>(g2p, dis);
    agg2_softmax<<<N_NODES / 64 + 1, 256, 0, stream>>>((const float4*)g2p, rs, re, csr_src, dis, b2, out);
}